// Round 1
// baseline (133.429 us; speedup 1.0000x reference)
//
#include <hip/hip_runtime.h>
#include <hip/hip_bf16.h>

#define B 16
#define N 10000
#define D 64
#define R 64
#define H 512
#define K 32
#define NBLK ((N + 255) / 256)   // 40

// ---------- ws layout (bytes) ----------
// oidx   : B*K int    @ 0        (2048)
// ow     : B*K f32    @ 2048     (2048)
// tm     : B*K*D f32  @ 4096     (131072)
// m2     : B*K f32    @ 135168   (2048)
// part   : B*NBLK f32 @ 137216   (2560)

__device__ __forceinline__ unsigned long long shfl_down_u64(unsigned long long x, int off) {
    unsigned lo = (unsigned)x, hi = (unsigned)(x >> 32);
    lo = __shfl_down(lo, off, 64);
    hi = __shfl_down(hi, off, 64);
    return ((unsigned long long)hi << 32) | lo;
}

// ---------------- kernel 1: exact top-K per batch row ----------------
__global__ void k_topk(const float* __restrict__ e, int* __restrict__ oidx,
                       float* __restrict__ ow) {
    const int b = blockIdx.x, tid = threadIdx.x;
    __shared__ float vals[N];
    __shared__ unsigned long long wpart[4];
    __shared__ int winner_s;

    for (int n = tid; n < N; n += 256) vals[n] = e[b * N + n];
    __syncthreads();

    // local best as packed key: (float bits << 32) | (0xFFFFFFFF - idx)
    // e >= 0 so float-bit ordering == value ordering; tie -> smaller idx wins.
    auto scan = [&]() -> unsigned long long {
        unsigned long long best = 0ull;
        for (int n = tid; n < N; n += 256) {
            float v = vals[n];
            if (v >= 0.f) {
                unsigned long long key =
                    ((unsigned long long)__float_as_uint(v) << 32) |
                    (unsigned)(0xFFFFFFFFu - (unsigned)n);
                if (key > best) best = key;
            }
        }
        return best;
    };

    unsigned long long best = scan();
    for (int sel = 0; sel < K; ++sel) {
        unsigned long long r = best;
        #pragma unroll
        for (int off = 32; off > 0; off >>= 1) {
            unsigned long long o = shfl_down_u64(r, off);
            if (o > r) r = o;
        }
        if ((tid & 63) == 0) wpart[tid >> 6] = r;
        __syncthreads();
        if (tid == 0) {
            unsigned long long w = wpart[0];
            #pragma unroll
            for (int i = 1; i < 4; ++i) if (wpart[i] > w) w = wpart[i];
            int widx = (int)(0xFFFFFFFFu - (unsigned)(w & 0xFFFFFFFFu));
            winner_s = widx;
            oidx[b * K + sel] = widx;
            ow[b * K + sel] = __uint_as_float((unsigned)(w >> 32));
        }
        __syncthreads();
        const int widx = winner_s;
        if ((widx & 255) == tid) {      // owner (stride-256 layout) rescans
            vals[widx] = -1.0f;
            best = scan();
        }
        __syncthreads();
    }
}

// ---------------- kernel 2: MLP on the selected rows only ----------------
// one block per (b,k): h = relu(W1 @ cat(r_b, s_idx) + b1); mean = W2 @ h + b2
__global__ void k_means(const float* __restrict__ rE, const float* __restrict__ sup,
                        const float* __restrict__ W1, const float* __restrict__ b1,
                        const float* __restrict__ W2, const float* __restrict__ b2,
                        const int* __restrict__ oidx, float* __restrict__ tm,
                        float* __restrict__ m2) {
    const int blk = blockIdx.x;
    const int b = blk >> 5, kk = blk & 31;
    const int tid = threadIdx.x;
    __shared__ float rs[R + D];     // [r(64) | s(64)]
    __shared__ float h[H];
    __shared__ float part[256];
    __shared__ float meanv[D];

    const int id = oidx[b * K + kk];
    if (tid < R) rs[tid] = rE[b * R + tid];
    else if (tid < R + D) rs[tid] = sup[id * D + (tid - R)];
    __syncthreads();

    for (int t = tid; t < H; t += 256) {
        const float* w = W1 + t * (R + D);
        float acc = b1[t];
        #pragma unroll
        for (int c = 0; c < R + D; c += 4) {
            float4 wv = *(const float4*)(w + c);
            acc += wv.x * rs[c] + wv.y * rs[c + 1] + wv.z * rs[c + 2] + wv.w * rs[c + 3];
        }
        h[t] = fmaxf(acc, 0.f);
    }
    __syncthreads();

    const int d = tid & 63, ch = tid >> 6;              // 64 d x 4 chunks
    const float* w2 = W2 + d * H + ch * 128;
    float acc = 0.f;
    #pragma unroll
    for (int c = 0; c < 128; c += 4) {
        float4 wv = *(const float4*)(w2 + c);
        const int hb = ch * 128 + c;
        acc += wv.x * h[hb] + wv.y * h[hb + 1] + wv.z * h[hb + 2] + wv.w * h[hb + 3];
    }
    part[tid] = acc;
    __syncthreads();
    if (tid < D) {
        float m = b2[d] + part[d] + part[64 + d] + part[128 + d] + part[192 + d];
        meanv[d] = m;
        tm[(b * K + kk) * D + d] = m;
    }
    __syncthreads();
    if (tid < 64) {
        float sq = meanv[tid] * meanv[tid];
        #pragma unroll
        for (int off = 32; off > 0; off >>= 1) sq += __shfl_down(sq, off, 64);
        if (tid == 0) m2[b * K + kk] = sq;
    }
}

// ---------------- kernel 3: RBF + weighted sum + per-block partials ----------------
__global__ void k_rbf(const float* __restrict__ sup, const float* __restrict__ tm,
                      const float* __restrict__ m2, const float* __restrict__ ow,
                      float* __restrict__ out, float* __restrict__ part) {
    const int b = blockIdx.y;
    const int tid = threadIdx.x;
    const int n = blockIdx.x * 256 + tid;
    __shared__ float4 stm[K * D / 4];    // 8KB: top_mean[b] as float4
    __shared__ float sw[K], sm2[K];
    __shared__ float red[256];

    const float4* tm4 = (const float4*)(tm + b * K * D);
    for (int i = tid; i < K * D / 4; i += 256) stm[i] = tm4[i];
    if (tid < K) { sw[tid] = ow[b * K + tid]; sm2[tid] = m2[b * K + tid]; }
    __syncthreads();

    float total = 0.f;
    if (n < N) {
        float4 s[16];
        const float4* sp = (const float4*)(sup + n * D);
        #pragma unroll
        for (int i = 0; i < 16; ++i) s[i] = sp[i];
        float s2 = 0.f;
        #pragma unroll
        for (int i = 0; i < 16; ++i)
            s2 += s[i].x * s[i].x + s[i].y * s[i].y + s[i].z * s[i].z + s[i].w * s[i].w;

        for (int k = 0; k < K; ++k) {
            const float4* mp = stm + k * 16;
            float4 a = {0.f, 0.f, 0.f, 0.f};
            #pragma unroll
            for (int i = 0; i < 16; ++i) {
                float4 m = mp[i];
                a.x += s[i].x * m.x; a.y += s[i].y * m.y;
                a.z += s[i].z * m.z; a.w += s[i].w * m.w;
            }
            const float dot = (a.x + a.y) + (a.z + a.w);
            const float sq = s2 + sm2[k] - 2.f * dot;
            total += sw[k] * __expf(-0.5f * sq);
        }
        out[b * N + n] = total;
    }

    red[tid] = total;
    __syncthreads();
    #pragma unroll
    for (int s = 128; s > 0; s >>= 1) {
        if (tid < s) red[tid] += red[tid + s];
        __syncthreads();
    }
    if (tid == 0) part[b * NBLK + blockIdx.x] = red[0];
}

// ---------------- kernel 4: normalize ----------------
__global__ void k_norm(float* __restrict__ out, const float* __restrict__ part) {
    const int b = blockIdx.y;
    const int n = blockIdx.x * 256 + threadIdx.x;
    __shared__ float s;
    if (threadIdx.x == 0) {
        float t = 0.f;
        for (int i = 0; i < NBLK; ++i) t += part[b * NBLK + i];
        s = t + 1e-10f;
    }
    __syncthreads();
    if (n < N) out[b * N + n] /= s;
}

extern "C" void kernel_launch(void* const* d_in, const int* in_sizes, int n_in,
                              void* d_out, int out_size, void* d_ws, size_t ws_size,
                              hipStream_t stream) {
    const float* e   = (const float*)d_in[0];
    const float* rE  = (const float*)d_in[1];
    const float* sup = (const float*)d_in[2];
    const float* W1  = (const float*)d_in[3];
    const float* b1  = (const float*)d_in[4];
    const float* W2  = (const float*)d_in[5];
    const float* b2  = (const float*)d_in[6];
    float* out = (float*)d_out;

    char* ws = (char*)d_ws;
    int*   oidx = (int*)(ws + 0);
    float* ow   = (float*)(ws + 2048);
    float* tm   = (float*)(ws + 4096);
    float* m2   = (float*)(ws + 135168);
    float* part = (float*)(ws + 137216);

    hipLaunchKernelGGL(k_topk, dim3(B), dim3(256), 0, stream, e, oidx, ow);
    hipLaunchKernelGGL(k_means, dim3(B * K), dim3(256), 0, stream,
                       rE, sup, W1, b1, W2, b2, oidx, tm, m2);
    hipLaunchKernelGGL(k_rbf, dim3(NBLK, B), dim3(256), 0, stream,
                       sup, tm, m2, ow, out, part);
    hipLaunchKernelGGL(k_norm, dim3(NBLK, B), dim3(256), 0, stream, out, part);
}

// Round 2
// 98.065 us; speedup vs baseline: 1.3606x; 1.3606x over previous
//
#include <hip/hip_runtime.h>
#include <hip/hip_bf16.h>

#define B 16
#define N 10000
#define D 64
#define R 64
#define H 512
#define K 32
#define NBLK ((N + 255) / 256)   // 40

typedef unsigned long long ull;

// ---------- ws layout (bytes) ----------
// oidx   : B*K int    @ 0        (2048)
// ow     : B*K f32    @ 2048     (2048)
// tm     : B*K*D f32  @ 4096     (131072)
// m2     : B*K f32    @ 135168   (2048)
// part   : B*NBLK f32 @ 137216   (2560)

// ---------------- kernel 1: exact top-K per batch row ----------------
// 16 waves/block, one block per batch. Each wave owns 625 elems in REGISTERS
// (10 u64 keys/lane), does 32 rounds of butterfly shfl-max (no barriers, no
// LDS in the loop). One barrier, then wave 0 merges 16*32=512 candidates.
// Key = (float_bits << 32) | (0xFFFFFFFF - idx): e >= 0 so float-bit order ==
// value order; tie -> smaller index wins (matches jax.lax.top_k).
__global__ __launch_bounds__(1024) void k_topk(const float* __restrict__ e,
                                               int* __restrict__ oidx,
                                               float* __restrict__ ow) {
    const int b = blockIdx.x;
    const int tid = threadIdx.x;
    const int wave = tid >> 6, lane = tid & 63;
    __shared__ ull cand[16 * K];

    const int base = wave * 625;            // 16 waves * 625 = 10000 exactly
    ull keys[10];
    #pragma unroll
    for (int i = 0; i < 10; ++i) {
        const int off = i * 64 + lane;
        ull key = 0ull;
        if (off < 625) {
            const float v = e[b * N + base + off];
            key = ((ull)__float_as_uint(v) << 32) |
                  (unsigned)(0xFFFFFFFFu - (unsigned)(base + off));
        }
        keys[i] = key;
    }
    ull best = 0ull;
    #pragma unroll
    for (int i = 0; i < 10; ++i) best = keys[i] > best ? keys[i] : best;

    for (int sel = 0; sel < K; ++sel) {
        ull w = best;
        #pragma unroll
        for (int off = 32; off > 0; off >>= 1) {
            ull o = __shfl_xor(w, off, 64);
            w = o > w ? o : w;
        }
        if (lane == 0) cand[wave * K + sel] = w;
        if (best == w && w) {               // unique winner lane: remove+rescan regs
            #pragma unroll
            for (int i = 0; i < 10; ++i) if (keys[i] == w) keys[i] = 0ull;
            best = 0ull;
            #pragma unroll
            for (int i = 0; i < 10; ++i) best = keys[i] > best ? keys[i] : best;
        }
    }
    __syncthreads();

    if (wave == 0) {                        // merge 512 candidates, 8 per lane
        ull k2[8];
        #pragma unroll
        for (int i = 0; i < 8; ++i) k2[i] = cand[lane * 8 + i];
        ull best2 = 0ull;
        #pragma unroll
        for (int i = 0; i < 8; ++i) best2 = k2[i] > best2 ? k2[i] : best2;

        for (int sel = 0; sel < K; ++sel) {
            ull w = best2;
            #pragma unroll
            for (int off = 32; off > 0; off >>= 1) {
                ull o = __shfl_xor(w, off, 64);
                w = o > w ? o : w;
            }
            if (lane == 0) {
                oidx[b * K + sel] = (int)(0xFFFFFFFFu - (unsigned)(w & 0xFFFFFFFFu));
                ow[b * K + sel] = __uint_as_float((unsigned)(w >> 32));
            }
            if (best2 == w && w) {
                #pragma unroll
                for (int i = 0; i < 8; ++i) if (k2[i] == w) k2[i] = 0ull;
                best2 = 0ull;
                #pragma unroll
                for (int i = 0; i < 8; ++i) best2 = k2[i] > best2 ? k2[i] : best2;
            }
        }
    }
}

// ---------------- kernel 2: MLP on the selected rows only ----------------
// one block per (b,k): h = relu(W1 @ cat(r_b, s_idx) + b1); mean = W2 @ h + b2
__global__ void k_means(const float* __restrict__ rE, const float* __restrict__ sup,
                        const float* __restrict__ W1, const float* __restrict__ b1,
                        const float* __restrict__ W2, const float* __restrict__ b2,
                        const int* __restrict__ oidx, float* __restrict__ tm,
                        float* __restrict__ m2) {
    const int blk = blockIdx.x;
    const int b = blk >> 5, kk = blk & 31;
    const int tid = threadIdx.x;
    __shared__ float rs[R + D];     // [r(64) | s(64)]
    __shared__ float h[H];
    __shared__ float part[256];
    __shared__ float meanv[D];

    const int id = oidx[b * K + kk];
    if (tid < R) rs[tid] = rE[b * R + tid];
    else if (tid < R + D) rs[tid] = sup[id * D + (tid - R)];
    __syncthreads();

    for (int t = tid; t < H; t += 256) {
        const float* w = W1 + t * (R + D);
        float acc = b1[t];
        #pragma unroll
        for (int c = 0; c < R + D; c += 4) {
            float4 wv = *(const float4*)(w + c);
            acc += wv.x * rs[c] + wv.y * rs[c + 1] + wv.z * rs[c + 2] + wv.w * rs[c + 3];
        }
        h[t] = fmaxf(acc, 0.f);
    }
    __syncthreads();

    const int d = tid & 63, ch = tid >> 6;              // 64 d x 4 chunks
    const float* w2 = W2 + d * H + ch * 128;
    float acc = 0.f;
    #pragma unroll
    for (int c = 0; c < 128; c += 4) {
        float4 wv = *(const float4*)(w2 + c);
        const int hb = ch * 128 + c;
        acc += wv.x * h[hb] + wv.y * h[hb + 1] + wv.z * h[hb + 2] + wv.w * h[hb + 3];
    }
    part[tid] = acc;
    __syncthreads();
    if (tid < D) {
        float m = b2[d] + part[d] + part[64 + d] + part[128 + d] + part[192 + d];
        meanv[d] = m;
        tm[(b * K + kk) * D + d] = m;
    }
    __syncthreads();
    if (tid < 64) {
        float sq = meanv[tid] * meanv[tid];
        #pragma unroll
        for (int off = 32; off > 0; off >>= 1) sq += __shfl_down(sq, off, 64);
        if (tid == 0) m2[b * K + kk] = sq;
    }
}

// ---------------- kernel 3: RBF + weighted sum + per-block partials ----------------
__global__ void k_rbf(const float* __restrict__ sup, const float* __restrict__ tm,
                      const float* __restrict__ m2, const float* __restrict__ ow,
                      float* __restrict__ out, float* __restrict__ part) {
    const int b = blockIdx.y;
    const int tid = threadIdx.x;
    const int n = blockIdx.x * 256 + tid;
    __shared__ float4 stm[K * D / 4];    // 8KB: top_mean[b] as float4
    __shared__ float sw[K], sm2[K];
    __shared__ float red[256];

    const float4* tm4 = (const float4*)(tm + b * K * D);
    for (int i = tid; i < K * D / 4; i += 256) stm[i] = tm4[i];
    if (tid < K) { sw[tid] = ow[b * K + tid]; sm2[tid] = m2[b * K + tid]; }
    __syncthreads();

    float total = 0.f;
    if (n < N) {
        float4 s[16];
        const float4* sp = (const float4*)(sup + n * D);
        #pragma unroll
        for (int i = 0; i < 16; ++i) s[i] = sp[i];
        float s2 = 0.f;
        #pragma unroll
        for (int i = 0; i < 16; ++i)
            s2 += s[i].x * s[i].x + s[i].y * s[i].y + s[i].z * s[i].z + s[i].w * s[i].w;

        for (int k = 0; k < K; ++k) {
            const float4* mp = stm + k * 16;
            float4 a = {0.f, 0.f, 0.f, 0.f};
            #pragma unroll
            for (int i = 0; i < 16; ++i) {
                float4 m = mp[i];
                a.x += s[i].x * m.x; a.y += s[i].y * m.y;
                a.z += s[i].z * m.z; a.w += s[i].w * m.w;
            }
            const float dot = (a.x + a.y) + (a.z + a.w);
            const float sq = s2 + sm2[k] - 2.f * dot;
            total += sw[k] * __expf(-0.5f * sq);
        }
        out[b * N + n] = total;
    }

    red[tid] = total;
    __syncthreads();
    #pragma unroll
    for (int s = 128; s > 0; s >>= 1) {
        if (tid < s) red[tid] += red[tid + s];
        __syncthreads();
    }
    if (tid == 0) part[b * NBLK + blockIdx.x] = red[0];
}

// ---------------- kernel 4: normalize ----------------
__global__ void k_norm(float* __restrict__ out, const float* __restrict__ part) {
    const int b = blockIdx.y;
    const int n = blockIdx.x * 256 + threadIdx.x;
    __shared__ float s;
    if (threadIdx.x == 0) {
        float t = 0.f;
        for (int i = 0; i < NBLK; ++i) t += part[b * NBLK + i];
        s = t + 1e-10f;
    }
    __syncthreads();
    if (n < N) out[b * N + n] /= s;
}

extern "C" void kernel_launch(void* const* d_in, const int* in_sizes, int n_in,
                              void* d_out, int out_size, void* d_ws, size_t ws_size,
                              hipStream_t stream) {
    const float* e   = (const float*)d_in[0];
    const float* rE  = (const float*)d_in[1];
    const float* sup = (const float*)d_in[2];
    const float* W1  = (const float*)d_in[3];
    const float* b1  = (const float*)d_in[4];
    const float* W2  = (const float*)d_in[5];
    const float* b2  = (const float*)d_in[6];
    float* out = (float*)d_out;

    char* ws = (char*)d_ws;
    int*   oidx = (int*)(ws + 0);
    float* ow   = (float*)(ws + 2048);
    float* tm   = (float*)(ws + 4096);
    float* m2   = (float*)(ws + 135168);
    float* part = (float*)(ws + 137216);

    hipLaunchKernelGGL(k_topk, dim3(B), dim3(1024), 0, stream, e, oidx, ow);
    hipLaunchKernelGGL(k_means, dim3(B * K), dim3(256), 0, stream,
                       rE, sup, W1, b1, W2, b2, oidx, tm, m2);
    hipLaunchKernelGGL(k_rbf, dim3(NBLK, B), dim3(256), 0, stream,
                       sup, tm, m2, ow, out, part);
    hipLaunchKernelGGL(k_norm, dim3(NBLK, B), dim3(256), 0, stream, out, part);
}

// Round 3
// 62.991 us; speedup vs baseline: 2.1182x; 1.5568x over previous
//
#include <hip/hip_runtime.h>
#include <hip/hip_bf16.h>

#define B 16
#define N 10000
#define D 64
#define R 64
#define H 512
#define K 32
#define NBLK ((N + 255) / 256)   // 40
#define NBUCK 4096

typedef unsigned long long ull;

// ---------- ws layout (bytes) ----------
// oidx   : B*K int    @ 0        (2048)
// ow     : B*K f32    @ 2048     (2048)
// tm     : B*K*D f32  @ 4096     (131072)
// m2     : B*K f32    @ 135168   (2048)
// part   : B*NBLK f32 @ 137216   (2560)

// ---------------- kernel 1: exact top-K set per batch row ----------------
// The downstream use is sum_k(w_k * prob_k) -> ORDER of the top-k is
// irrelevant, only the SET. Keys (value_bits<<32 | ~idx) are distinct, so
// the set is exact and jax's smaller-index tie-break is preserved.
// Histogram select: bucket = v*4096 (monotone on [0,1)); threshold bucket t
// s.t. suffix count >= K; candidates (bucket >= t, expected ~40) ranked by
// key-compare in LDS; rank < K -> selected, rank = output slot.
__global__ __launch_bounds__(1024) void k_topk(const float* __restrict__ e,
                                               int* __restrict__ oidx,
                                               float* __restrict__ ow) {
    const int b = blockIdx.x, tid = threadIdx.x;
    __shared__ unsigned hist[NBUCK];
    __shared__ ull cand[1024];
    __shared__ unsigned cnt;
    __shared__ int tsh;

    #pragma unroll
    for (int i = 0; i < NBUCK / 1024; ++i) hist[tid + i * 1024] = 0;
    if (tid == 0) cnt = 0;

    // load, key, bucket — keys stay in registers for pass 2
    ull keys[10];
    int bkt[10];
    #pragma unroll
    for (int i = 0; i < 10; ++i) {
        const int n = tid + i * 1024;
        keys[i] = 0ull; bkt[i] = -1;
        if (n < N) {
            const float v = e[b * N + n];
            keys[i] = ((ull)__float_as_uint(v) << 32) |
                      (unsigned)(0xFFFFFFFFu - (unsigned)n);
            int bu = (int)(v * (float)NBUCK);
            bkt[i] = bu > NBUCK - 1 ? NBUCK - 1 : (bu < 0 ? 0 : bu);
        }
    }
    __syncthreads();
    #pragma unroll
    for (int i = 0; i < 10; ++i) if (bkt[i] >= 0) atomicAdd(&hist[bkt[i]], 1u);
    __syncthreads();

    if (tid == 0) {   // expected ~14 iterations for uniform data
        unsigned s = 0; int t = 0;
        for (int j = NBUCK - 1; j >= 0; --j) {
            s += hist[j];
            if (s >= K) { t = j; break; }
        }
        tsh = t;
    }
    __syncthreads();
    const int t = tsh;

    #pragma unroll
    for (int i = 0; i < 10; ++i)
        if (bkt[i] >= t) {
            unsigned p = atomicAdd(&cnt, 1u);
            if (p < 1024u) cand[p] = keys[i];
        }
    __syncthreads();

    const unsigned C = cnt < 1024u ? cnt : 1024u;
    if (tid < (int)C) {
        const ull mine = cand[tid];
        int rank = 0;
        for (unsigned j = 0; j < C; ++j) rank += (cand[j] > mine);
        if (rank < K) {
            oidx[b * K + rank] = (int)(0xFFFFFFFFu - (unsigned)(mine & 0xFFFFFFFFu));
            ow[b * K + rank] = __uint_as_float((unsigned)(mine >> 32));
        }
    }
}

// ---------------- kernel 2: MLP on the selected rows only ----------------
// one block per (b,k): h = relu(W1 @ cat(r_b, s_idx) + b1); mean = W2 @ h + b2
__global__ void k_means(const float* __restrict__ rE, const float* __restrict__ sup,
                        const float* __restrict__ W1, const float* __restrict__ b1,
                        const float* __restrict__ W2, const float* __restrict__ b2,
                        const int* __restrict__ oidx, float* __restrict__ tm,
                        float* __restrict__ m2) {
    const int blk = blockIdx.x;
    const int b = blk >> 5, kk = blk & 31;
    const int tid = threadIdx.x;
    __shared__ float rs[R + D];     // [r(64) | s(64)]
    __shared__ float h[H];
    __shared__ float part[256];
    __shared__ float meanv[D];

    const int id = oidx[b * K + kk];
    if (tid < R) rs[tid] = rE[b * R + tid];
    else if (tid < R + D) rs[tid] = sup[id * D + (tid - R)];
    __syncthreads();

    for (int t = tid; t < H; t += 256) {
        const float* w = W1 + t * (R + D);
        float acc = b1[t];
        #pragma unroll
        for (int c = 0; c < R + D; c += 4) {
            float4 wv = *(const float4*)(w + c);
            acc += wv.x * rs[c] + wv.y * rs[c + 1] + wv.z * rs[c + 2] + wv.w * rs[c + 3];
        }
        h[t] = fmaxf(acc, 0.f);
    }
    __syncthreads();

    const int d = tid & 63, ch = tid >> 6;              // 64 d x 4 chunks
    const float* w2 = W2 + d * H + ch * 128;
    float acc = 0.f;
    #pragma unroll
    for (int c = 0; c < 128; c += 4) {
        float4 wv = *(const float4*)(w2 + c);
        const int hb = ch * 128 + c;
        acc += wv.x * h[hb] + wv.y * h[hb + 1] + wv.z * h[hb + 2] + wv.w * h[hb + 3];
    }
    part[tid] = acc;
    __syncthreads();
    if (tid < D) {
        float m = b2[d] + part[d] + part[64 + d] + part[128 + d] + part[192 + d];
        meanv[d] = m;
        tm[(b * K + kk) * D + d] = m;
    }
    __syncthreads();
    if (tid < 64) {
        float sq = meanv[tid] * meanv[tid];
        #pragma unroll
        for (int off = 32; off > 0; off >>= 1) sq += __shfl_down(sq, off, 64);
        if (tid == 0) m2[b * K + kk] = sq;
    }
}

// ---------------- kernel 3: RBF + weighted sum + per-block partials ----------------
__global__ void k_rbf(const float* __restrict__ sup, const float* __restrict__ tm,
                      const float* __restrict__ m2, const float* __restrict__ ow,
                      float* __restrict__ out, float* __restrict__ part) {
    const int b = blockIdx.y;
    const int tid = threadIdx.x;
    const int n = blockIdx.x * 256 + tid;
    __shared__ float4 stm[K * D / 4];    // 8KB: top_mean[b] as float4
    __shared__ float sw[K], sm2[K];
    __shared__ float red[256];

    const float4* tm4 = (const float4*)(tm + b * K * D);
    for (int i = tid; i < K * D / 4; i += 256) stm[i] = tm4[i];
    if (tid < K) { sw[tid] = ow[b * K + tid]; sm2[tid] = m2[b * K + tid]; }
    __syncthreads();

    float total = 0.f;
    if (n < N) {
        float4 s[16];
        const float4* sp = (const float4*)(sup + n * D);
        #pragma unroll
        for (int i = 0; i < 16; ++i) s[i] = sp[i];
        float s2 = 0.f;
        #pragma unroll
        for (int i = 0; i < 16; ++i)
            s2 += s[i].x * s[i].x + s[i].y * s[i].y + s[i].z * s[i].z + s[i].w * s[i].w;

        for (int k = 0; k < K; ++k) {
            const float4* mp = stm + k * 16;
            float4 a = {0.f, 0.f, 0.f, 0.f};
            #pragma unroll
            for (int i = 0; i < 16; ++i) {
                float4 m = mp[i];
                a.x += s[i].x * m.x; a.y += s[i].y * m.y;
                a.z += s[i].z * m.z; a.w += s[i].w * m.w;
            }
            const float dot = (a.x + a.y) + (a.z + a.w);
            const float sq = s2 + sm2[k] - 2.f * dot;
            total += sw[k] * __expf(-0.5f * sq);
        }
        out[b * N + n] = total;
    }

    red[tid] = total;
    __syncthreads();
    #pragma unroll
    for (int s = 128; s > 0; s >>= 1) {
        if (tid < s) red[tid] += red[tid + s];
        __syncthreads();
    }
    if (tid == 0) part[b * NBLK + blockIdx.x] = red[0];
}

// ---------------- kernel 4: normalize ----------------
__global__ void k_norm(float* __restrict__ out, const float* __restrict__ part) {
    const int b = blockIdx.y;
    const int n = blockIdx.x * 256 + threadIdx.x;
    __shared__ float s;
    if (threadIdx.x == 0) {
        float t = 0.f;
        for (int i = 0; i < NBLK; ++i) t += part[b * NBLK + i];
        s = t + 1e-10f;
    }
    __syncthreads();
    if (n < N) out[b * N + n] /= s;
}

extern "C" void kernel_launch(void* const* d_in, const int* in_sizes, int n_in,
                              void* d_out, int out_size, void* d_ws, size_t ws_size,
                              hipStream_t stream) {
    const float* e   = (const float*)d_in[0];
    const float* rE  = (const float*)d_in[1];
    const float* sup = (const float*)d_in[2];
    const float* W1  = (const float*)d_in[3];
    const float* b1  = (const float*)d_in[4];
    const float* W2  = (const float*)d_in[5];
    const float* b2  = (const float*)d_in[6];
    float* out = (float*)d_out;

    char* ws = (char*)d_ws;
    int*   oidx = (int*)(ws + 0);
    float* ow   = (float*)(ws + 2048);
    float* tm   = (float*)(ws + 4096);
    float* m2   = (float*)(ws + 135168);
    float* part = (float*)(ws + 137216);

    hipLaunchKernelGGL(k_topk, dim3(B), dim3(1024), 0, stream, e, oidx, ow);
    hipLaunchKernelGGL(k_means, dim3(B * K), dim3(256), 0, stream,
                       rE, sup, W1, b1, W2, b2, oidx, tm, m2);
    hipLaunchKernelGGL(k_rbf, dim3(NBLK, B), dim3(256), 0, stream,
                       sup, tm, m2, ow, out, part);
    hipLaunchKernelGGL(k_norm, dim3(NBLK, B), dim3(256), 0, stream, out, part);
}

// Round 4
// 61.754 us; speedup vs baseline: 2.1607x; 1.0200x over previous
//
#include <hip/hip_runtime.h>
#include <hip/hip_bf16.h>

#define B 16
#define N 10000
#define D 64
#define R 64
#define H 512
#define K 32
#define NBLK ((N + 255) / 256)   // 40
#define NBUCK 4096

typedef unsigned long long ull;

// ---------- ws layout (bytes) ----------
// oidx   : B*K int    @ 0        (2048)
// ow     : B*K f32    @ 2048     (2048)
// tm     : B*K*D f32  @ 4096     (131072)
// nm2    : B*K f32    @ 135168   (-0.5*||mean||^2)
// part   : B*NBLK f32 @ 137216   (2560)
// rp     : B*H f32    @ 139776   (b1 + r_b @ W1[:, :R].T)

// ---------------- kernel 1: exact top-K set + r_part ----------------
// Top-k SET via histogram select (order irrelevant downstream; rank gives
// value-determined output slots, ties -> smaller idx wins like jax).
// Tail: computes rp[b][t] = b1[t] + sum_r rE[b][r] * W1[t][r]  (shared by
// all 32 k of this b -> halves k_means' W1 work).
__global__ __launch_bounds__(1024) void k_topk(const float* __restrict__ e,
                                               const float* __restrict__ rE,
                                               const float* __restrict__ W1,
                                               const float* __restrict__ b1,
                                               int* __restrict__ oidx,
                                               float* __restrict__ ow,
                                               float* __restrict__ rp) {
    const int b = blockIdx.x, tid = threadIdx.x;
    __shared__ unsigned hist[NBUCK];
    __shared__ ull cand[1024];
    __shared__ float rEs[R];
    __shared__ unsigned cnt;
    __shared__ int tsh;

    #pragma unroll
    for (int i = 0; i < NBUCK / 1024; ++i) hist[tid + i * 1024] = 0;
    if (tid == 0) cnt = 0;
    if (tid < R) rEs[tid] = rE[b * R + tid];

    ull keys[10];
    int bkt[10];
    #pragma unroll
    for (int i = 0; i < 10; ++i) {
        const int n = tid + i * 1024;
        keys[i] = 0ull; bkt[i] = -1;
        if (n < N) {
            const float v = e[b * N + n];
            keys[i] = ((ull)__float_as_uint(v) << 32) |
                      (unsigned)(0xFFFFFFFFu - (unsigned)n);
            int bu = (int)(v * (float)NBUCK);
            bkt[i] = bu > NBUCK - 1 ? NBUCK - 1 : (bu < 0 ? 0 : bu);
        }
    }
    __syncthreads();
    #pragma unroll
    for (int i = 0; i < 10; ++i) if (bkt[i] >= 0) atomicAdd(&hist[bkt[i]], 1u);
    __syncthreads();

    // wave 0: parallel suffix scan from the top, 64 buckets per step
    if (tid < 64) {
        unsigned acc = 0;
        for (int w = 0; w < NBUCK / 64; ++w) {
            const int j = NBUCK - 1 - (w * 64 + tid);
            unsigned p = hist[j];
            #pragma unroll
            for (int off = 1; off < 64; off <<= 1) {
                unsigned o = __shfl_up(p, off, 64);
                if (tid >= off) p += o;
            }
            const ull mask = __ballot(acc + p >= K);
            if (mask) {
                if (tid == 0) {
                    const int l0 = __ffsll((long long)mask) - 1;
                    tsh = NBUCK - 1 - (w * 64 + l0);
                }
                break;
            }
            acc += (unsigned)__shfl((int)p, 63, 64);
        }
    }
    __syncthreads();
    const int t = tsh;

    #pragma unroll
    for (int i = 0; i < 10; ++i)
        if (bkt[i] >= t) {
            unsigned p = atomicAdd(&cnt, 1u);
            if (p < 1024u) cand[p] = keys[i];
        }
    __syncthreads();

    const unsigned C = cnt < 1024u ? cnt : 1024u;
    if (tid < (int)C) {
        const ull mine = cand[tid];
        int rank = 0;
        for (unsigned j = 0; j < C; ++j) rank += (cand[j] > mine);
        if (rank < K) {
            oidx[b * K + rank] = (int)(0xFFFFFFFFu - (unsigned)(mine & 0xFFFFFFFFu));
            ow[b * K + rank] = __uint_as_float((unsigned)(mine >> 32));
        }
    }

    // r_part tail (independent of selection; rEs was written pre-barrier)
    if (tid < H) {
        const float4* w = (const float4*)(W1 + tid * (R + D));  // cols 0..R
        float acc = b1[tid];
        #pragma unroll
        for (int i = 0; i < R / 4; ++i) {
            const float4 wv = w[i];
            acc += wv.x * rEs[4 * i] + wv.y * rEs[4 * i + 1] +
                   wv.z * rEs[4 * i + 2] + wv.w * rEs[4 * i + 3];
        }
        rp[b * H + tid] = acc;
    }
}

// ---------------- kernel 2: MLP on selected rows (2 pairs/block) ----------------
// block = (b, pair of 2 k). h = relu(rp + W1[:,R:] @ s); mean = W2 @ h + b2.
__global__ __launch_bounds__(512) void k_means(
        const float* __restrict__ sup, const float* __restrict__ W1,
        const float* __restrict__ W2, const float* __restrict__ b2,
        const int* __restrict__ oidx, const float* __restrict__ rp,
        float* __restrict__ tm, float* __restrict__ nm2) {
    const int b = blockIdx.x >> 4, pr = blockIdx.x & 15;
    const int gk = b * K + pr * 2;
    const int tid = threadIdx.x;
    __shared__ float sA[D], sB[D];
    __shared__ float hA[H], hB[H];
    __shared__ float partA[512], partB[512];

    const int id0 = oidx[gk], id1 = oidx[gk + 1];
    if (tid < D) sA[tid] = sup[id0 * D + tid];
    else if (tid < 2 * D) sB[tid - D] = sup[id1 * D + (tid - D)];
    __syncthreads();

    {   // phase 1: one h-row per thread, weight row read once for both pairs
        const float4* w = (const float4*)(W1 + tid * (R + D) + R);
        float a0 = rp[b * H + tid], a1 = a0;
        #pragma unroll
        for (int i = 0; i < D / 4; ++i) {
            const float4 wv = w[i];
            a0 += wv.x * sA[4 * i] + wv.y * sA[4 * i + 1] +
                  wv.z * sA[4 * i + 2] + wv.w * sA[4 * i + 3];
            a1 += wv.x * sB[4 * i] + wv.y * sB[4 * i + 1] +
                  wv.z * sB[4 * i + 2] + wv.w * sB[4 * i + 3];
        }
        hA[tid] = fmaxf(a0, 0.f);
        hB[tid] = fmaxf(a1, 0.f);
    }
    __syncthreads();

    {   // phase 2: d = tid&63, 8 chunks of 64 over H
        const int d = tid & 63, ch = tid >> 6;
        const float4* w2 = (const float4*)(W2 + d * H + ch * 64);
        float a0 = 0.f, a1 = 0.f;
        #pragma unroll
        for (int i = 0; i < 16; ++i) {
            const float4 wv = w2[i];
            const int hb = ch * 64 + 4 * i;
            a0 += wv.x * hA[hb] + wv.y * hA[hb + 1] + wv.z * hA[hb + 2] + wv.w * hA[hb + 3];
            a1 += wv.x * hB[hb] + wv.y * hB[hb + 1] + wv.z * hB[hb + 2] + wv.w * hB[hb + 3];
        }
        partA[tid] = a0;
        partB[tid] = a1;
    }
    __syncthreads();

    if (tid < 128) {            // wave 0 -> pair 0, wave 1 -> pair 1
        const int d = tid & 63, w = tid >> 6;
        const float* part = w == 0 ? partA : partB;
        float m = b2[d];
        #pragma unroll
        for (int c = 0; c < 8; ++c) m += part[c * 64 + d];
        tm[(gk + w) * D + d] = m;
        float sq = m * m;
        #pragma unroll
        for (int off = 32; off > 0; off >>= 1) sq += __shfl_down(sq, off, 64);
        if (d == 0) nm2[gk + w] = -0.5f * sq;
    }
}

// ---------------- kernel 3: RBF + weighted sum + per-block partials ----------------
// mean/weight reads are wave-uniform -> scalar-cache/L1 broadcast; no LDS staging.
__global__ __launch_bounds__(256) void k_rbf(
        const float* __restrict__ sup, const float* __restrict__ tm,
        const float* __restrict__ nm2, const float* __restrict__ ow,
        float* __restrict__ out, float* __restrict__ part) {
    const int b = blockIdx.y;
    const int tid = threadIdx.x;
    const int n = blockIdx.x * 256 + tid;
    __shared__ float wsum[4];

    float total = 0.f;
    if (n < N) {
        float4 s[16];
        const float4* sp = (const float4*)(sup + n * D);
        #pragma unroll
        for (int i = 0; i < 16; ++i) s[i] = sp[i];
        float s2 = 0.f;
        #pragma unroll
        for (int i = 0; i < 16; ++i)
            s2 += s[i].x * s[i].x + s[i].y * s[i].y + s[i].z * s[i].z + s[i].w * s[i].w;
        const float ns2 = -0.5f * s2;

        const float4* tmb = (const float4*)(tm + b * K * D);
        #pragma unroll 2
        for (int k = 0; k < K; ++k) {
            const float4* mp = tmb + k * 16;
            float4 a = {0.f, 0.f, 0.f, 0.f};
            #pragma unroll
            for (int i = 0; i < 16; ++i) {
                const float4 m = mp[i];
                a.x += s[i].x * m.x; a.y += s[i].y * m.y;
                a.z += s[i].z * m.z; a.w += s[i].w * m.w;
            }
            const float dot = (a.x + a.y) + (a.z + a.w);
            const float arg = ns2 + nm2[b * K + k] + dot;   // = -0.5*sqdist <= 0
            total += ow[b * K + k] * __expf(arg);
        }
        out[b * N + n] = total;
    }

    // block reduction: wave shuffle + 4 partials
    float v = total;
    #pragma unroll
    for (int off = 32; off > 0; off >>= 1) v += __shfl_down(v, off, 64);
    if ((tid & 63) == 0) wsum[tid >> 6] = v;
    __syncthreads();
    if (tid == 0)
        part[b * NBLK + blockIdx.x] = (wsum[0] + wsum[1]) + (wsum[2] + wsum[3]);
}

// ---------------- kernel 4: normalize ----------------
__global__ void k_norm(float* __restrict__ out, const float* __restrict__ part) {
    const int b = blockIdx.y;
    const int n = blockIdx.x * 256 + threadIdx.x;
    const int tid = threadIdx.x;
    __shared__ float sdiv;
    if (tid < 64) {
        float v = (tid < NBLK) ? part[b * NBLK + tid] : 0.f;
        #pragma unroll
        for (int off = 32; off > 0; off >>= 1) v += __shfl_down(v, off, 64);
        if (tid == 0) sdiv = 1.f / (v + 1e-10f);
    }
    __syncthreads();
    if (n < N) out[b * N + n] *= sdiv;
}

extern "C" void kernel_launch(void* const* d_in, const int* in_sizes, int n_in,
                              void* d_out, int out_size, void* d_ws, size_t ws_size,
                              hipStream_t stream) {
    const float* e   = (const float*)d_in[0];
    const float* rE  = (const float*)d_in[1];
    const float* sup = (const float*)d_in[2];
    const float* W1  = (const float*)d_in[3];
    const float* b1  = (const float*)d_in[4];
    const float* W2  = (const float*)d_in[5];
    const float* b2  = (const float*)d_in[6];
    float* out = (float*)d_out;

    char* ws = (char*)d_ws;
    int*   oidx = (int*)(ws + 0);
    float* ow   = (float*)(ws + 2048);
    float* tm   = (float*)(ws + 4096);
    float* nm2  = (float*)(ws + 135168);
    float* part = (float*)(ws + 137216);
    float* rp   = (float*)(ws + 139776);

    hipLaunchKernelGGL(k_topk, dim3(B), dim3(1024), 0, stream,
                       e, rE, W1, b1, oidx, ow, rp);
    hipLaunchKernelGGL(k_means, dim3(B * 16), dim3(512), 0, stream,
                       sup, W1, W2, b2, oidx, rp, tm, nm2);
    hipLaunchKernelGGL(k_rbf, dim3(NBLK, B), dim3(256), 0, stream,
                       sup, tm, nm2, ow, out, part);
    hipLaunchKernelGGL(k_norm, dim3(NBLK, B), dim3(256), 0, stream, out, part);
}

// Round 5
// 55.609 us; speedup vs baseline: 2.3994x; 1.1105x over previous
//
#include <hip/hip_runtime.h>
#include <hip/hip_bf16.h>

#define B 16
#define N 10000
#define D 64
#define R 64
#define H 512
#define K 32
#define NBLK ((N + 255) / 256)   // 40
#define NBUCK 4096

typedef unsigned long long ull;

// ---------- ws layout (bytes) ----------
// oidx   : B*K int    @ 0        (2048)
// ow     : B*K f32    @ 2048     (2048)
// tm     : B*K*D f32  @ 4096     (131072)
// nm2    : B*K f32    @ 135168   (-0.5*||mean||^2)
// part   : B*NBLK f32 @ 137216   (2560)
// rp     : B*H f32    @ 139776   (b1 + r_b @ W1[:, :R].T)

// ---------------- kernel 1: exact top-K set + r_part ----------------
__global__ __launch_bounds__(1024) void k_topk(const float* __restrict__ e,
                                               const float* __restrict__ rE,
                                               const float* __restrict__ W1,
                                               const float* __restrict__ b1,
                                               int* __restrict__ oidx,
                                               float* __restrict__ ow,
                                               float* __restrict__ rp) {
    const int b = blockIdx.x, tid = threadIdx.x;
    __shared__ unsigned hist[NBUCK];
    __shared__ ull cand[1024];
    __shared__ float rEs[R];
    __shared__ unsigned cnt;
    __shared__ int tsh;

    #pragma unroll
    for (int i = 0; i < NBUCK / 1024; ++i) hist[tid + i * 1024] = 0;
    if (tid == 0) cnt = 0;
    if (tid < R) rEs[tid] = rE[b * R + tid];

    ull keys[10];
    int bkt[10];
    #pragma unroll
    for (int i = 0; i < 10; ++i) {
        const int n = tid + i * 1024;
        keys[i] = 0ull; bkt[i] = -1;
        if (n < N) {
            const float v = e[b * N + n];
            keys[i] = ((ull)__float_as_uint(v) << 32) |
                      (unsigned)(0xFFFFFFFFu - (unsigned)n);
            int bu = (int)(v * (float)NBUCK);
            bkt[i] = bu > NBUCK - 1 ? NBUCK - 1 : (bu < 0 ? 0 : bu);
        }
    }
    __syncthreads();
    #pragma unroll
    for (int i = 0; i < 10; ++i) if (bkt[i] >= 0) atomicAdd(&hist[bkt[i]], 1u);
    __syncthreads();

    // wave 0: parallel suffix scan from the top, 64 buckets per step
    if (tid < 64) {
        unsigned acc = 0;
        for (int w = 0; w < NBUCK / 64; ++w) {
            const int j = NBUCK - 1 - (w * 64 + tid);
            unsigned p = hist[j];
            #pragma unroll
            for (int off = 1; off < 64; off <<= 1) {
                unsigned o = __shfl_up(p, off, 64);
                if (tid >= off) p += o;
            }
            const ull mask = __ballot(acc + p >= K);
            if (mask) {
                if (tid == 0) {
                    const int l0 = __ffsll((long long)mask) - 1;
                    tsh = NBUCK - 1 - (w * 64 + l0);
                }
                break;
            }
            acc += (unsigned)__shfl((int)p, 63, 64);
        }
    }
    __syncthreads();
    const int t = tsh;

    #pragma unroll
    for (int i = 0; i < 10; ++i)
        if (bkt[i] >= t) {
            unsigned p = atomicAdd(&cnt, 1u);
            if (p < 1024u) cand[p] = keys[i];
        }
    __syncthreads();

    const unsigned C = cnt < 1024u ? cnt : 1024u;
    if (tid < (int)C) {
        const ull mine = cand[tid];
        int rank = 0;
        for (unsigned j = 0; j < C; ++j) rank += (cand[j] > mine);
        if (rank < K) {
            oidx[b * K + rank] = (int)(0xFFFFFFFFu - (unsigned)(mine & 0xFFFFFFFFu));
            ow[b * K + rank] = __uint_as_float((unsigned)(mine >> 32));
        }
    }

    // r_part tail (independent of selection; rEs was written pre-barrier)
    if (tid < H) {
        const float4* w = (const float4*)(W1 + tid * (R + D));  // cols 0..R
        float acc = b1[tid];
        #pragma unroll
        for (int i = 0; i < R / 4; ++i) {
            const float4 wv = w[i];
            acc += wv.x * rEs[4 * i] + wv.y * rEs[4 * i + 1] +
                   wv.z * rEs[4 * i + 2] + wv.w * rEs[4 * i + 3];
        }
        rp[b * H + tid] = acc;
    }
}

// ---------------- kernel 2: MLP on selected rows (2 pairs/block) ----------------
__global__ __launch_bounds__(512) void k_means(
        const float* __restrict__ sup, const float* __restrict__ W1,
        const float* __restrict__ W2, const float* __restrict__ b2,
        const int* __restrict__ oidx, const float* __restrict__ rp,
        float* __restrict__ tm, float* __restrict__ nm2) {
    const int b = blockIdx.x >> 4, pr = blockIdx.x & 15;
    const int gk = b * K + pr * 2;
    const int tid = threadIdx.x;
    __shared__ float sA[D], sB[D];
    __shared__ float hA[H], hB[H];
    __shared__ float partA[512], partB[512];

    const int id0 = oidx[gk], id1 = oidx[gk + 1];
    if (tid < D) sA[tid] = sup[id0 * D + tid];
    else if (tid < 2 * D) sB[tid - D] = sup[id1 * D + (tid - D)];
    __syncthreads();

    {   // phase 1: one h-row per thread, weight row read once for both pairs
        const float4* w = (const float4*)(W1 + tid * (R + D) + R);
        float a0 = rp[b * H + tid], a1 = a0;
        #pragma unroll
        for (int i = 0; i < D / 4; ++i) {
            const float4 wv = w[i];
            a0 += wv.x * sA[4 * i] + wv.y * sA[4 * i + 1] +
                  wv.z * sA[4 * i + 2] + wv.w * sA[4 * i + 3];
            a1 += wv.x * sB[4 * i] + wv.y * sB[4 * i + 1] +
                  wv.z * sB[4 * i + 2] + wv.w * sB[4 * i + 3];
        }
        hA[tid] = fmaxf(a0, 0.f);
        hB[tid] = fmaxf(a1, 0.f);
    }
    __syncthreads();

    {   // phase 2: d = tid&63, 8 chunks of 64 over H
        const int d = tid & 63, ch = tid >> 6;
        const float4* w2 = (const float4*)(W2 + d * H + ch * 64);
        float a0 = 0.f, a1 = 0.f;
        #pragma unroll
        for (int i = 0; i < 16; ++i) {
            const float4 wv = w2[i];
            const int hb = ch * 64 + 4 * i;
            a0 += wv.x * hA[hb] + wv.y * hA[hb + 1] + wv.z * hA[hb + 2] + wv.w * hA[hb + 3];
            a1 += wv.x * hB[hb] + wv.y * hB[hb + 1] + wv.z * hB[hb + 2] + wv.w * hB[hb + 3];
        }
        partA[tid] = a0;
        partB[tid] = a1;
    }
    __syncthreads();

    if (tid < 128) {            // wave 0 -> pair 0, wave 1 -> pair 1
        const int d = tid & 63, w = tid >> 6;
        const float* part = w == 0 ? partA : partB;
        float m = b2[d];
        #pragma unroll
        for (int c = 0; c < 8; ++c) m += part[c * 64 + d];
        tm[(gk + w) * D + d] = m;
        float sq = m * m;
        #pragma unroll
        for (int off = 32; off > 0; off >>= 1) sq += __shfl_down(sq, off, 64);
        if (d == 0) nm2[gk + w] = -0.5f * sq;
    }
}

// ---------------- kernel 3: RBF, d-outer / k-inner, acc[K] in VGPRs ----------------
// m/nm2/ow reads are wave-uniform -> SMEM (s_load) pipe, free broadcast; only
// one 16-float chunk of s is live at a time so s stays register-resident.
__global__ __launch_bounds__(256) void k_rbf(
        const float* __restrict__ sup, const float* __restrict__ tm,
        const float* __restrict__ nm2, const float* __restrict__ ow,
        float* __restrict__ out, float* __restrict__ part) {
    const int b = blockIdx.y;
    const int tid = threadIdx.x;
    const int n = blockIdx.x * 256 + tid;
    __shared__ float wsum[4];

    const int nc = n < N ? n : N - 1;        // clamp: invalid lanes compute, don't store
    const float4* sp = (const float4*)(sup + nc * D);
    const float* tmb = tm + b * K * D;

    float acc[K];
    #pragma unroll
    for (int k = 0; k < K; ++k) acc[k] = 0.f;
    float s2 = 0.f;

    #pragma unroll
    for (int dc = 0; dc < 4; ++dc) {
        const float4 s0 = sp[dc * 4 + 0];
        const float4 s1 = sp[dc * 4 + 1];
        const float4 s2v = sp[dc * 4 + 2];
        const float4 s3 = sp[dc * 4 + 3];
        s2 += s0.x * s0.x + s0.y * s0.y + s0.z * s0.z + s0.w * s0.w
            + s1.x * s1.x + s1.y * s1.y + s1.z * s1.z + s1.w * s1.w
            + s2v.x * s2v.x + s2v.y * s2v.y + s2v.z * s2v.z + s2v.w * s2v.w
            + s3.x * s3.x + s3.y * s3.y + s3.z * s3.z + s3.w * s3.w;
        #pragma unroll
        for (int k = 0; k < K; ++k) {
            const float4* mp = (const float4*)(tmb + k * D + dc * 16);
            const float4 m0 = mp[0], m1 = mp[1], m2 = mp[2], m3 = mp[3];
            acc[k] += s0.x * m0.x + s0.y * m0.y + s0.z * m0.z + s0.w * m0.w
                    + s1.x * m1.x + s1.y * m1.y + s1.z * m1.z + s1.w * m1.w
                    + s2v.x * m2.x + s2v.y * m2.y + s2v.z * m2.z + s2v.w * m2.w
                    + s3.x * m3.x + s3.y * m3.y + s3.z * m3.z + s3.w * m3.w;
        }
    }

    const float ns2 = -0.5f * s2;
    float total = 0.f;
    #pragma unroll
    for (int k = 0; k < K; ++k) {
        const float arg = ns2 + nm2[b * K + k] + acc[k];   // = -0.5*sqdist
        total += ow[b * K + k] * __expf(arg);
    }
    if (n < N) out[b * N + n] = total;
    else total = 0.f;

    // block reduction: wave shuffle + 4 partials
    float v = total;
    #pragma unroll
    for (int off = 32; off > 0; off >>= 1) v += __shfl_down(v, off, 64);
    if ((tid & 63) == 0) wsum[tid >> 6] = v;
    __syncthreads();
    if (tid == 0)
        part[b * NBLK + blockIdx.x] = (wsum[0] + wsum[1]) + (wsum[2] + wsum[3]);
}

// ---------------- kernel 4: normalize ----------------
__global__ void k_norm(float* __restrict__ out, const float* __restrict__ part) {
    const int b = blockIdx.y;
    const int n = blockIdx.x * 256 + threadIdx.x;
    const int tid = threadIdx.x;
    __shared__ float sdiv;
    if (tid < 64) {
        float v = (tid < NBLK) ? part[b * NBLK + tid] : 0.f;
        #pragma unroll
        for (int off = 32; off > 0; off >>= 1) v += __shfl_down(v, off, 64);
        if (tid == 0) sdiv = 1.f / (v + 1e-10f);
    }
    __syncthreads();
    if (n < N) out[b * N + n] *= sdiv;
}

extern "C" void kernel_launch(void* const* d_in, const int* in_sizes, int n_in,
                              void* d_out, int out_size, void* d_ws, size_t ws_size,
                              hipStream_t stream) {
    const float* e   = (const float*)d_in[0];
    const float* rE  = (const float*)d_in[1];
    const float* sup = (const float*)d_in[2];
    const float* W1  = (const float*)d_in[3];
    const float* b1  = (const float*)d_in[4];
    const float* W2  = (const float*)d_in[5];
    const float* b2  = (const float*)d_in[6];
    float* out = (float*)d_out;

    char* ws = (char*)d_ws;
    int*   oidx = (int*)(ws + 0);
    float* ow   = (float*)(ws + 2048);
    float* tm   = (float*)(ws + 4096);
    float* nm2  = (float*)(ws + 135168);
    float* part = (float*)(ws + 137216);
    float* rp   = (float*)(ws + 139776);

    hipLaunchKernelGGL(k_topk, dim3(B), dim3(1024), 0, stream,
                       e, rE, W1, b1, oidx, ow, rp);
    hipLaunchKernelGGL(k_means, dim3(B * 16), dim3(512), 0, stream,
                       sup, W1, W2, b2, oidx, rp, tm, nm2);
    hipLaunchKernelGGL(k_rbf, dim3(NBLK, B), dim3(256), 0, stream,
                       sup, tm, nm2, ow, out, part);
    hipLaunchKernelGGL(k_norm, dim3(NBLK, B), dim3(256), 0, stream, out, part);
}